// Round 5
// baseline (1337.528 us; speedup 1.0000x reference)
//
#include <hip/hip_runtime.h>

// ---------------------------------------------------------------------------
// TrajectoryDecoder: B=4096, F=256, H=256, M=3, T=30 (T read from device)
// out = [trajectories (B,M,T,2) fp32][mode_probs (B,M) fp32]
// R19: occupancy attack. R18 proved B-load latency is NOT the stall (staged
// DMA pipeline = exactly R14's 894us); R16 never tested occupancy (2 blocks/
// CU halved tile -> doubled L2 traffic, still 2 waves/SIMD). This round:
// SAME 64-row x 1-mode tile, SAME per-CU weight traffic, but 1024 threads =
// 16 waves = 4 waves/SIMD. Wave owns 16 gate-cols (acc 64 f32 -> AGPR 64);
// __launch_bounds__(1024,4) caps 128 regs/wave. B-tiles via SGPR-uniform
// bases (readfirstlane) + lane-offset VGPR + imm offsets to keep arch VGPRs
// ~50. Staging/vmcnt machinery dropped (R18: neutral, +3pt VALU). 4 barriers
// /step, h0 dbuf. Per-acc accumulation order bitwise R14-identical.
// ---------------------------------------------------------------------------

typedef __attribute__((ext_vector_type(8))) short bf16x8;
typedef __attribute__((ext_vector_type(4))) float f32x4;

__device__ __forceinline__ short f2bf(float f) {
    unsigned u = __builtin_bit_cast(unsigned, f);
    unsigned r = (u + 0x7fffu + ((u >> 16) & 1u)) >> 16;
    return (short)r;
}
__device__ __forceinline__ float bf2f(short s) {
    unsigned u = ((unsigned)(unsigned short)s) << 16;
    return __builtin_bit_cast(float, u);
}
__device__ __forceinline__ float fast_sigmoid(float x) {
    x = fminf(fmaxf(x, -30.f), 30.f);
    float e = __builtin_amdgcn_exp2f(x * -1.442695041f);
    return __builtin_amdgcn_rcpf(1.f + e);
}
__device__ __forceinline__ float fast_tanh(float x) {
    x = fminf(fmaxf(x, -15.f), 15.f);
    float e = __builtin_amdgcn_exp2f(x * -2.885390082f);
    return (1.f - e) * __builtin_amdgcn_rcpf(1.f + e);
}

// ---------------------------------------------------------------------------
// Weight prep: fp32 -> bf16, B-fragment consumption order (R14 layout).
// Regions (1KB blocks):
//   P0  [0,1152):    w_hh0 per (m,w8): 48 = [rz: ks*4+t (32)][n: 32+ks*2+nt]
//   P1  [1152,3456): per (m,w8): 96 = [rz: half*32+ks*4+t (64)]
//                                     [xn: 64+ks*2+nt][hn: 80+ks*2+nt]
//   PC  [3456,4608): w_ih0[:,2:258] per (m,w8): 48 = [ks*6+t6]
// ---------------------------------------------------------------------------
__global__ void prep_kernel(const float* __restrict__ w_ih0,
                            const float* __restrict__ w_hh0,
                            const float* __restrict__ w_ih1,
                            const float* __restrict__ w_hh1,
                            short* __restrict__ ws) {
    int bid = blockIdx.x;
    int L = threadIdx.x;
    const float* src;
    int srcRowLen, colBase, m, w, ks, t;
    if (bid < 1152) {
        int idx = bid, mw = idx / 48, blk = idx % 48;
        m = mw / 8; w = mw % 8;
        if (blk < 32) { ks = blk >> 2; t = blk & 3; }
        else { int q = blk - 32; ks = q >> 1; t = 4 + (q & 1); }
        src = w_hh0 + (size_t)m * 768 * 256; srcRowLen = 256; colBase = 0;
    } else if (bid < 3456) {
        int idx = bid - 1152, mw = idx / 96, blk = idx % 96;
        m = mw / 8; w = mw % 8;
        int half;
        if (blk < 64) { half = blk >> 5; ks = (blk >> 2) & 7; t = blk & 3; }
        else { int q = blk - 64; half = q >> 4; ks = (q >> 1) & 7; t = 4 + (q & 1); }
        src = (half ? w_hh1 : w_ih1) + (size_t)m * 768 * 256;
        srcRowLen = 256; colBase = 0;
    } else {
        int idx = bid - 3456, mw = idx / 48, blk = idx % 48;
        m = mw / 8; w = mw % 8; ks = blk / 6; t = blk % 6;
        src = w_ih0 + (size_t)m * 768 * 258; srcRowLen = 258; colBase = 2;
    }
    int row = (t >> 1) * 256 + 32 * w + (t & 1) * 16 + (L & 15);
    int col0 = colBase + ks * 32 + (L >> 4) * 8;
    short* dst = ws + (size_t)bid * 512 + L * 8;
    const float* s = src + (size_t)row * srcRowLen + col0;
#pragma unroll
    for (int j = 0; j < 8; ++j) dst[j] = f2bf(s[j]);
}

// ---------------------------------------------------------------------------
// Mode-probability MLP
// ---------------------------------------------------------------------------
__global__ __launch_bounds__(256) void modeprobs_kernel(
    const float* __restrict__ ctx, const float* __restrict__ w1,
    const float* __restrict__ b1, const float* __restrict__ w2,
    const float* __restrict__ b2, float* __restrict__ out,
    long probs_off) {
    __shared__ float w1s[64 * 256];
    int tid = threadIdx.x;
    int j = tid & 63;
    int rsub = tid >> 6;
#pragma unroll
    for (int i = 0; i < 64; ++i) w1s[tid + i * 256] = w1[tid + i * 256];
    float b1v = b1[j];
    float w2v0 = w2[j], w2v1 = w2[64 + j], w2v2 = w2[128 + j];
    float b20 = b2[0], b21 = b2[1], b22 = b2[2];
    __syncthreads();
    for (int c = 0; c < 16; ++c) {
        int brow = blockIdx.x * 64 + c * 4 + rsub;
        const float* crow = ctx + (size_t)brow * 256;
        float accv = b1v;
#pragma unroll 8
        for (int k = 0; k < 256; ++k) {
            int kk = (k + j) & 255;
            accv += w1s[j * 256 + kk] * crow[kk];
        }
        float h = fmaxf(accv, 0.f);
        float l0 = h * w2v0, l1 = h * w2v1, l2 = h * w2v2;
#pragma unroll
        for (int s = 1; s < 64; s <<= 1) {
            l0 += __shfl_xor(l0, s);
            l1 += __shfl_xor(l1, s);
            l2 += __shfl_xor(l2, s);
        }
        if (j == 0) {
            l0 += b20; l1 += b21; l2 += b22;
            float mx = fmaxf(l0, fmaxf(l1, l2));
            float e0 = __builtin_amdgcn_exp2f((l0 - mx) * 1.442695041f);
            float e1 = __builtin_amdgcn_exp2f((l1 - mx) * 1.442695041f);
            float e2 = __builtin_amdgcn_exp2f((l2 - mx) * 1.442695041f);
            float inv = 1.f / (e0 + e1 + e2);
            out[probs_off + (size_t)brow * 3 + 0] = e0 * inv;
            out[probs_off + (size_t)brow * 3 + 1] = e1 * inv;
            out[probs_off + (size_t)brow * 3 + 2] = e2 * inv;
        }
    }
}

// ---------------------------------------------------------------------------
// Persistent GRU decoder. Block = 64 batch rows x 1 mode; 1024 threads
// (16 waves = 4/SIMD). Wave wv: w8 = wv>>1 selects R14's wave-group, hh =
// wv&1 selects the 16-col half; wave owns col cA = 32*w8 + 16*hh + lr of
// each gate. Per ks: 6 B-tiles (3 x-side, 3 h-side), 24 MFMA. B addressing:
// SGPR-uniform bases + lane*16B voffset + imm (tile stride 1KB).
// ---------------------------------------------------------------------------
__global__ __launch_bounds__(1024, 4) void decoder_kernel(
    const float* __restrict__ context,
    const float* __restrict__ w_ih0_f,   // (3,768,258): pos-weight cols 0..1
    const float* __restrict__ b_ih0, const float* __restrict__ b_hh0,
    const float* __restrict__ b_ih1, const float* __restrict__ b_hh1,
    const float* __restrict__ out_w, const float* __restrict__ out_b,
    const short* __restrict__ ws, float* __restrict__ out,
    const int* __restrict__ pT, int ntiles) {
    __shared__ short ctxS[64 * 264];   // read-only after init
    __shared__ short h0a[64 * 264], h0b[64 * 264];  // double-buffered h0
    __shared__ short h1s[64 * 264];
    __shared__ float posD[128];
    __shared__ float owl[512];
    __shared__ short cwp0h[768], cwp1h[768];  // w_ih0[:,0],[:,1] as bf16
    __shared__ float cbA[512];                // L0 rz: b_ih0+b_hh0
    __shared__ float cb1A[512];               // L1 rz: b_ih1+b_hh1
    __shared__ short cbXn[256], cbh0n[256];   // L0 n biases (bf16)
    __shared__ short cb1X[256], cb1H[256];    // L1 n biases (bf16)

    const int bid = blockIdx.x;
    const int xcd = bid & 7, slot = bid >> 3;
    int mode, xl, nx;
    if (xcd < 3)      { mode = 0; xl = xcd;     nx = 3; }
    else if (xcd < 6) { mode = 1; xl = xcd - 3; nx = 3; }
    else              { mode = 2; xl = xcd - 6; nx = 2; }
    const int g = slot * nx + xl;
    if (g >= ntiles) return;
    const int m = mode;
    const int b0 = g * 64;

    const int T = *pT;
    const int tid = threadIdx.x;
    const int lane = tid & 63, wv = tid >> 6;   // wv in [0,16)
    const int w8 = wv >> 1, hh = wv & 1;
    const int lr = lane & 15, quad = lane >> 4;
    const int cA = 32 * w8 + 16 * hh + lr;      // this wave's gate column

    if (tid < 128) posD[tid] = 0.f;
    if (tid < 512) {
        owl[tid] = out_w[m * 512 + tid];
        cbA[tid] = b_ih0[m * 768 + tid] + b_hh0[m * 768 + tid];
        cb1A[tid] = b_ih1[m * 768 + tid] + b_hh1[m * 768 + tid];
    }
    if (tid < 256) {
        cbXn[tid] = f2bf(b_ih0[m * 768 + 512 + tid]);
        cbh0n[tid] = f2bf(b_hh0[m * 768 + 512 + tid]);
        cb1X[tid] = f2bf(b_ih1[m * 768 + 512 + tid]);
        cb1H[tid] = f2bf(b_hh1[m * 768 + 512 + tid]);
    }
    if (tid < 768) {
        cwp0h[tid] = f2bf(w_ih0_f[((size_t)m * 768 + tid) * 258 + 0]);
        cwp1h[tid] = f2bf(w_ih0_f[((size_t)m * 768 + tid) * 258 + 1]);
    }
#pragma unroll
    for (int i = 0; i < 16; ++i) {
        int idx = tid + i * 1024;
        int r = idx >> 8, k = idx & 255;
        short v = f2bf(context[(size_t)(b0 + r) * 256 + k]);
        ctxS[r * 264 + k] = v;
        h0a[r * 264 + k] = v;
        h1s[r * 264 + k] = v;
    }
    const float ob0v = out_b[m * 2 + 0], ob1v = out_b[m * 2 + 1];

    // Wave-uniform B-tile bases (SGPR via readfirstlane), in shorts.
    const int base0 =
        __builtin_amdgcn_readfirstlane(((m * 8 + w8) * 48 + hh) * 512);
    const int base1 = __builtin_amdgcn_readfirstlane(
        (1152 + (m * 8 + w8) * 96 + hh) * 512);
    const int basec = __builtin_amdgcn_readfirstlane(
        (3456 + (m * 8 + w8) * 48 + hh) * 512);
    const short* pH = ws + base0;               // w_hh0 rz: imm {0,2*512}/ks
    const short* pHn = ws + base0 + 32 * 512;   // w_hh0 n:  imm {0}/ks
    const short* pI1 = ws + base1;              // w_ih1 rz
    const short* pQ1 = ws + base1 + 32 * 512;   // w_hh1 rz
    const short* pX1 = ws + base1 + 64 * 512;   // w_ih1 xn
    const short* pN1 = ws + base1 + 80 * 512;   // w_hh1 hn
    const short* pC = ws + basec;               // ctx: rz {0,2*512}, xn {4*512}
    const int lv = lane * 8;                    // per-lane element offset

    __syncthreads();

    float cum0 = 0.f, cum1 = 0.f;

    for (int st = 0; st < T; ++st) {
        const short* h0c = (st & 1) ? h0b : h0a;   // current h0
        short* h0n_ = (st & 1) ? h0a : h0b;        // next h0 (no WAR hazard)

        // ======== layer 0 (merged rz+n; wave = one 16-col slice) ========
        {
            f32x4 arz[2][4], axn[4], ahn[4];
            const int cz = 256 + cA, cn = 512 + cA;
            const float bAr = cbA[cA], bAz = cbA[cz];
            const float w0r = bf2f(cwp0h[cA]), w1r = bf2f(cwp1h[cA]);
            const float w0z = bf2f(cwp0h[cz]), w1z = bf2f(cwp1h[cz]);
            const float w0n = bf2f(cwp0h[cn]), w1n = bf2f(cwp1h[cn]);
            const float bXn = bf2f(cbXn[cA]), bHn = bf2f(cbh0n[cA]);
#pragma unroll
            for (int rt = 0; rt < 4; ++rt)
#pragma unroll
                for (int r = 0; r < 4; ++r) {
                    int row = rt * 16 + quad * 4 + r;
                    float px = posD[row * 2], py = posD[row * 2 + 1];
                    arz[0][rt][r] = bAr + px * w0r + py * w1r;
                    arz[1][rt][r] = bAz + px * w0z + py * w1z;
                    axn[rt][r] = bXn + px * w0n + py * w1n;
                    ahn[rt][r] = bHn;
                }
            const short* qC = pC;
            const short* qH = pH;
            const short* qHn = pHn;
#pragma unroll 1
            for (int ks = 0; ks < 8; ++ks) {
                bf16x8 a[4];
                {
                    bf16x8 b0 = *reinterpret_cast<const bf16x8*>(qC + lv);
                    bf16x8 b1 = *reinterpret_cast<const bf16x8*>(qC + lv + 2 * 512);
                    bf16x8 b2 = *reinterpret_cast<const bf16x8*>(qC + lv + 4 * 512);
#pragma unroll
                    for (int rt = 0; rt < 4; ++rt)
                        a[rt] = *reinterpret_cast<const bf16x8*>(
                            ctxS + (rt * 16 + lr) * 264 + ks * 32 + quad * 8);
#pragma unroll
                    for (int rt = 0; rt < 4; ++rt)
                        arz[0][rt] = __builtin_amdgcn_mfma_f32_16x16x32_bf16(
                            a[rt], b0, arz[0][rt], 0, 0, 0);
#pragma unroll
                    for (int rt = 0; rt < 4; ++rt)
                        arz[1][rt] = __builtin_amdgcn_mfma_f32_16x16x32_bf16(
                            a[rt], b1, arz[1][rt], 0, 0, 0);
#pragma unroll
                    for (int rt = 0; rt < 4; ++rt)
                        axn[rt] = __builtin_amdgcn_mfma_f32_16x16x32_bf16(
                            a[rt], b2, axn[rt], 0, 0, 0);
                }
                {
                    bf16x8 c0 = *reinterpret_cast<const bf16x8*>(qH + lv);
                    bf16x8 c1 = *reinterpret_cast<const bf16x8*>(qH + lv + 2 * 512);
                    bf16x8 c2 = *reinterpret_cast<const bf16x8*>(qHn + lv);
#pragma unroll
                    for (int rt = 0; rt < 4; ++rt)
                        a[rt] = *reinterpret_cast<const bf16x8*>(
                            h0c + (rt * 16 + lr) * 264 + ks * 32 + quad * 8);
#pragma unroll
                    for (int rt = 0; rt < 4; ++rt)
                        arz[0][rt] = __builtin_amdgcn_mfma_f32_16x16x32_bf16(
                            a[rt], c0, arz[0][rt], 0, 0, 0);
#pragma unroll
                    for (int rt = 0; rt < 4; ++rt)
                        arz[1][rt] = __builtin_amdgcn_mfma_f32_16x16x32_bf16(
                            a[rt], c1, arz[1][rt], 0, 0, 0);
#pragma unroll
                    for (int rt = 0; rt < 4; ++rt)
                        ahn[rt] = __builtin_amdgcn_mfma_f32_16x16x32_bf16(
                            a[rt], c2, ahn[rt], 0, 0, 0);
                }
                qC += 6 * 512;
                qH += 4 * 512;
                qHn += 2 * 512;
            }
            // no barrier: epilogue writes h0n_ (other buffer), no WAR hazard
#pragma unroll
            for (int rt = 0; rt < 4; ++rt)
#pragma unroll
                for (int r = 0; r < 4; ++r) {
                    int row = rt * 16 + quad * 4 + r;
                    float rr = fast_sigmoid(arz[0][rt][r]);
                    float zz = fast_sigmoid(arz[1][rt][r]);
                    float nn = fast_tanh(axn[rt][r] + rr * ahn[rt][r]);
                    float hold = bf2f(h0c[row * 264 + cA]);
                    h0n_[row * 264 + cA] = f2bf((1.f - zz) * nn + zz * hold);
                }
        }
        __syncthreads();  // B1: h0' visible

        // ======== layer 1 (merged rz+n) ========
        {
            f32x4 arz[2][4], axn[4], ahn[4];
            const int cz = 256 + cA;
            const float bAr = cb1A[cA], bAz = cb1A[cz];
            const float bXv = bf2f(cb1X[cA]), bHv = bf2f(cb1H[cA]);
#pragma unroll
            for (int rt = 0; rt < 4; ++rt)
#pragma unroll
                for (int r = 0; r < 4; ++r) {
                    arz[0][rt][r] = bAr;
                    arz[1][rt][r] = bAz;
                    axn[rt][r] = bXv;
                    ahn[rt][r] = bHv;
                }
            const short* qI = pI1;
            const short* qQ = pQ1;
            const short* qX = pX1;
            const short* qN = pN1;
#pragma unroll 1
            for (int ks = 0; ks < 8; ++ks) {
                bf16x8 a[4];
                {
                    bf16x8 b0 = *reinterpret_cast<const bf16x8*>(qI + lv);
                    bf16x8 b1 = *reinterpret_cast<const bf16x8*>(qI + lv + 2 * 512);
                    bf16x8 b2 = *reinterpret_cast<const bf16x8*>(qX + lv);
#pragma unroll
                    for (int rt = 0; rt < 4; ++rt)
                        a[rt] = *reinterpret_cast<const bf16x8*>(
                            h0n_ + (rt * 16 + lr) * 264 + ks * 32 + quad * 8);
#pragma unroll
                    for (int rt = 0; rt < 4; ++rt)
                        arz[0][rt] = __builtin_amdgcn_mfma_f32_16x16x32_bf16(
                            a[rt], b0, arz[0][rt], 0, 0, 0);
#pragma unroll
                    for (int rt = 0; rt < 4; ++rt)
                        arz[1][rt] = __builtin_amdgcn_mfma_f32_16x16x32_bf16(
                            a[rt], b1, arz[1][rt], 0, 0, 0);
#pragma unroll
                    for (int rt = 0; rt < 4; ++rt)
                        axn[rt] = __builtin_amdgcn_mfma_f32_16x16x32_bf16(
                            a[rt], b2, axn[rt], 0, 0, 0);
                }
                {
                    bf16x8 c0 = *reinterpret_cast<const bf16x8*>(qQ + lv);
                    bf16x8 c1 = *reinterpret_cast<const bf16x8*>(qQ + lv + 2 * 512);
                    bf16x8 c2 = *reinterpret_cast<const bf16x8*>(qN + lv);
#pragma unroll
                    for (int rt = 0; rt < 4; ++rt)
                        a[rt] = *reinterpret_cast<const bf16x8*>(
                            h1s + (rt * 16 + lr) * 264 + ks * 32 + quad * 8);
#pragma unroll
                    for (int rt = 0; rt < 4; ++rt)
                        arz[0][rt] = __builtin_amdgcn_mfma_f32_16x16x32_bf16(
                            a[rt], c0, arz[0][rt], 0, 0, 0);
#pragma unroll
                    for (int rt = 0; rt < 4; ++rt)
                        arz[1][rt] = __builtin_amdgcn_mfma_f32_16x16x32_bf16(
                            a[rt], c1, arz[1][rt], 0, 0, 0);
#pragma unroll
                    for (int rt = 0; rt < 4; ++rt)
                        ahn[rt] = __builtin_amdgcn_mfma_f32_16x16x32_bf16(
                            a[rt], c2, ahn[rt], 0, 0, 0);
                }
                qI += 4 * 512;
                qQ += 4 * 512;
                qX += 2 * 512;
                qN += 2 * 512;
            }
            __syncthreads();  // B2: all h1 reads complete
#pragma unroll
            for (int rt = 0; rt < 4; ++rt)
#pragma unroll
                for (int r = 0; r < 4; ++r) {
                    int row = rt * 16 + quad * 4 + r;
                    float rr = fast_sigmoid(arz[0][rt][r]);
                    float zz = fast_sigmoid(arz[1][rt][r]);
                    float nn = fast_tanh(axn[rt][r] + rr * ahn[rt][r]);
                    float hold = bf2f(h1s[row * 264 + cA]);
                    h1s[row * 264 + cA] = f2bf((1.f - zz) * nn + zz * hold);
                }
        }
        __syncthreads();  // B3: h1' visible

        // ---------------- delta = h1' @ ow.T + ob ; cumsum -> out
        {
            int brow = tid >> 4, p = tid & 15;   // 64 rows x 16 partials
            float d0 = 0.f, d1 = 0.f;
#pragma unroll
            for (int j = 0; j < 2; ++j) {
                int cb = ((p + brow) & 15) * 16 + j * 8;
                bf16x8 hv8 = *reinterpret_cast<const bf16x8*>(h1s + brow * 264 + cb);
#pragma unroll
                for (int i = 0; i < 8; ++i) {
                    float hv = bf2f(hv8[i]);
                    d0 += hv * owl[cb + i];
                    d1 += hv * owl[256 + cb + i];
                }
            }
            d0 += __shfl_xor(d0, 1); d0 += __shfl_xor(d0, 2);
            d0 += __shfl_xor(d0, 4); d0 += __shfl_xor(d0, 8);
            d1 += __shfl_xor(d1, 1); d1 += __shfl_xor(d1, 2);
            d1 += __shfl_xor(d1, 4); d1 += __shfl_xor(d1, 8);
            d0 += ob0v;
            d1 += ob1v;
            if (p == 0) {
                cum0 += d0;
                cum1 += d1;
                size_t o = (((size_t)(b0 + brow) * 3 + m) * (size_t)T + st) * 2;
                out[o] = cum0;
                out[o + 1] = cum1;
                posD[brow * 2] = d0;
                posD[brow * 2 + 1] = d1;
            }
        }
        __syncthreads();  // B4: posD ready
    }
}

extern "C" void kernel_launch(void* const* d_in, const int* in_sizes, int n_in,
                              void* d_out, int out_size, void* d_ws, size_t ws_size,
                              hipStream_t stream) {
    const float* context = (const float*)d_in[0];
    const float* mp_w1 = (const float*)d_in[1];
    const float* mp_b1 = (const float*)d_in[2];
    const float* mp_w2 = (const float*)d_in[3];
    const float* mp_b2 = (const float*)d_in[4];
    const float* w_ih0 = (const float*)d_in[5];
    const float* w_hh0 = (const float*)d_in[6];
    const float* b_ih0 = (const float*)d_in[7];
    const float* b_hh0 = (const float*)d_in[8];
    const float* w_ih1 = (const float*)d_in[9];
    const float* w_hh1 = (const float*)d_in[10];
    const float* b_ih1 = (const float*)d_in[11];
    const float* b_hh1 = (const float*)d_in[12];
    const float* out_w = (const float*)d_in[13];
    const float* out_b = (const float*)d_in[14];
    const int* pT = (const int*)d_in[15];
    float* out = (float*)d_out;
    short* ws = (short*)d_ws;

    const int B = in_sizes[0] / 256;                      // 4096
    const int ntiles = B / 64;                            // 64
    const long probs_off = (long)out_size - (long)B * 3;

    prep_kernel<<<4608, 64, 0, stream>>>(w_ih0, w_hh0, w_ih1, w_hh1, ws);
    modeprobs_kernel<<<B / 64, 256, 0, stream>>>(context, mp_w1, mp_b1, mp_w2,
                                                 mp_b2, out, probs_off);
    const int nslots = (ntiles + 1) / 2;
    decoder_kernel<<<8 * nslots, 1024, 0, stream>>>(
        context, w_ih0, b_ih0, b_hh0, b_ih1, b_hh1, out_w, out_b, ws, out, pT,
        ntiles);
}

// Round 6
// 1072.865 us; speedup vs baseline: 1.2467x; 1.2467x over previous
//
#include <hip/hip_runtime.h>

// ---------------------------------------------------------------------------
// TrajectoryDecoder: B=4096, F=256, H=256, M=3, T=30 (T read from device)
// out = [trajectories (B,M,T,2) fp32][mode_probs (B,M) fp32]
// R20: R19's occupancy attack (1024 thr, 16 waves = 4/SIMD, wave owns 16
// gate-cols, acc 64) with strict register discipline so it actually fits
// 128 regs/wave (R19 spilled: FETCH 248MB scratch):
//  (1) NEW prep layout: per-(m,w8,hh) contiguous 96-tile stream in exact
//      consumption order -> ONE running B pointer (+3KB twice per ks),
//      tile selects are +0/+512/+1024 imm. (was 7 pointer streams)
//  (2) per-lane bias/cwp scalars re-read from LDS at each step init
//      (not held across the step loop).
//  (3) 3 B-tiles per half-iteration, A-frags (16 regs) reused x/h side.
// Budget: 64 acc + 16 A + <=24 B + ~15 misc ~= 119 <= 128.
// MFMA order per output element bitwise R14-identical.
// ---------------------------------------------------------------------------

typedef __attribute__((ext_vector_type(8))) short bf16x8;
typedef __attribute__((ext_vector_type(4))) float f32x4;

__device__ __forceinline__ short f2bf(float f) {
    unsigned u = __builtin_bit_cast(unsigned, f);
    unsigned r = (u + 0x7fffu + ((u >> 16) & 1u)) >> 16;
    return (short)r;
}
__device__ __forceinline__ float bf2f(short s) {
    unsigned u = ((unsigned)(unsigned short)s) << 16;
    return __builtin_bit_cast(float, u);
}
__device__ __forceinline__ float fast_sigmoid(float x) {
    x = fminf(fmaxf(x, -30.f), 30.f);
    float e = __builtin_amdgcn_exp2f(x * -1.442695041f);
    return __builtin_amdgcn_rcpf(1.f + e);
}
__device__ __forceinline__ float fast_tanh(float x) {
    x = fminf(fmaxf(x, -15.f), 15.f);
    float e = __builtin_amdgcn_exp2f(x * -2.885390082f);
    return (1.f - e) * __builtin_amdgcn_rcpf(1.f + e);
}

// ---------------------------------------------------------------------------
// Weight prep v2: fp32 -> bf16, stream-ordered per (m, w8, hh).
// Stream (96 tiles x 1KB) = [L0: ks(8) x {xr,xz,xn, hr,hz,hn}]
//                           [L1: ks(8) x {ir,iz,ix, qr,qz,qn}]
// Tile content (16-col B fragment, 16x16x32): lane L holds
//   B[k0 + (L>>4)*8 + j][g*256 + 32*w8 + 16*hh + (L&15)]  j=0..7
// grid 4608 = 3*16*96; bid = sidx*96 + t96 so dst = ws + bid*512 + L*8.
// ---------------------------------------------------------------------------
__global__ void prep_kernel(const float* __restrict__ w_ih0,
                            const float* __restrict__ w_hh0,
                            const float* __restrict__ w_ih1,
                            const float* __restrict__ w_hh1,
                            short* __restrict__ ws) {
    int bid = blockIdx.x;
    int L = threadIdx.x;
    int sidx = bid / 96, t96 = bid % 96;
    int m = sidx >> 4, rest = sidx & 15;
    int w8 = rest >> 1, hh = rest & 1;
    int layer = t96 / 48, t48 = t96 % 48;
    int ks = t48 / 6, slot = t48 % 6;
    int side = slot / 3, g = slot % 3;

    const float* src;
    int rowLen, colBase;
    if (layer == 0) {
        if (side == 0) { src = w_ih0 + (size_t)m * 768 * 258; rowLen = 258; colBase = 2; }
        else           { src = w_hh0 + (size_t)m * 768 * 256; rowLen = 256; colBase = 0; }
    } else {
        if (side == 0) { src = w_ih1 + (size_t)m * 768 * 256; rowLen = 256; colBase = 0; }
        else           { src = w_hh1 + (size_t)m * 768 * 256; rowLen = 256; colBase = 0; }
    }
    int row = g * 256 + 32 * w8 + 16 * hh + (L & 15);
    int col0 = colBase + ks * 32 + (L >> 4) * 8;
    short* dst = ws + (size_t)bid * 512 + L * 8;
    const float* s = src + (size_t)row * rowLen + col0;
#pragma unroll
    for (int j = 0; j < 8; ++j) dst[j] = f2bf(s[j]);
}

// ---------------------------------------------------------------------------
// Mode-probability MLP
// ---------------------------------------------------------------------------
__global__ __launch_bounds__(256) void modeprobs_kernel(
    const float* __restrict__ ctx, const float* __restrict__ w1,
    const float* __restrict__ b1, const float* __restrict__ w2,
    const float* __restrict__ b2, float* __restrict__ out,
    long probs_off) {
    __shared__ float w1s[64 * 256];
    int tid = threadIdx.x;
    int j = tid & 63;
    int rsub = tid >> 6;
#pragma unroll
    for (int i = 0; i < 64; ++i) w1s[tid + i * 256] = w1[tid + i * 256];
    float b1v = b1[j];
    float w2v0 = w2[j], w2v1 = w2[64 + j], w2v2 = w2[128 + j];
    float b20 = b2[0], b21 = b2[1], b22 = b2[2];
    __syncthreads();
    for (int c = 0; c < 16; ++c) {
        int brow = blockIdx.x * 64 + c * 4 + rsub;
        const float* crow = ctx + (size_t)brow * 256;
        float accv = b1v;
#pragma unroll 8
        for (int k = 0; k < 256; ++k) {
            int kk = (k + j) & 255;
            accv += w1s[j * 256 + kk] * crow[kk];
        }
        float h = fmaxf(accv, 0.f);
        float l0 = h * w2v0, l1 = h * w2v1, l2 = h * w2v2;
#pragma unroll
        for (int s = 1; s < 64; s <<= 1) {
            l0 += __shfl_xor(l0, s);
            l1 += __shfl_xor(l1, s);
            l2 += __shfl_xor(l2, s);
        }
        if (j == 0) {
            l0 += b20; l1 += b21; l2 += b22;
            float mx = fmaxf(l0, fmaxf(l1, l2));
            float e0 = __builtin_amdgcn_exp2f((l0 - mx) * 1.442695041f);
            float e1 = __builtin_amdgcn_exp2f((l1 - mx) * 1.442695041f);
            float e2 = __builtin_amdgcn_exp2f((l2 - mx) * 1.442695041f);
            float inv = 1.f / (e0 + e1 + e2);
            out[probs_off + (size_t)brow * 3 + 0] = e0 * inv;
            out[probs_off + (size_t)brow * 3 + 1] = e1 * inv;
            out[probs_off + (size_t)brow * 3 + 2] = e2 * inv;
        }
    }
}

// ---------------------------------------------------------------------------
// Persistent GRU decoder. Block = 64 batch rows x 1 mode; 1024 threads
// (16 waves = 4/SIMD). Wave (w8 = wv>>1, hh = wv&1) owns gate-col
// cA = 32*w8 + 16*hh + lr. Single stream pointer per layer.
// ---------------------------------------------------------------------------
__global__ __launch_bounds__(1024, 4) void decoder_kernel(
    const float* __restrict__ context,
    const float* __restrict__ w_ih0_f,   // (3,768,258): pos-weight cols 0..1
    const float* __restrict__ b_ih0, const float* __restrict__ b_hh0,
    const float* __restrict__ b_ih1, const float* __restrict__ b_hh1,
    const float* __restrict__ out_w, const float* __restrict__ out_b,
    const short* __restrict__ ws, float* __restrict__ out,
    const int* __restrict__ pT, int ntiles) {
    __shared__ short ctxS[64 * 264];   // read-only after init
    __shared__ short h0a[64 * 264], h0b[64 * 264];  // double-buffered h0
    __shared__ short h1s[64 * 264];
    __shared__ float posD[128];
    __shared__ float owl[512];
    __shared__ short cwp0h[768], cwp1h[768];  // w_ih0[:,0],[:,1] as bf16
    __shared__ float cbA[512];                // L0 rz: b_ih0+b_hh0
    __shared__ float cb1A[512];               // L1 rz: b_ih1+b_hh1
    __shared__ short cbXn[256], cbh0n[256];   // L0 n biases (bf16)
    __shared__ short cb1X[256], cb1H[256];    // L1 n biases (bf16)

    const int bid = blockIdx.x;
    const int xcd = bid & 7, slot = bid >> 3;
    int mode, xl, nx;
    if (xcd < 3)      { mode = 0; xl = xcd;     nx = 3; }
    else if (xcd < 6) { mode = 1; xl = xcd - 3; nx = 3; }
    else              { mode = 2; xl = xcd - 6; nx = 2; }
    const int g = slot * nx + xl;
    if (g >= ntiles) return;
    const int m = mode;
    const int b0 = g * 64;

    const int T = *pT;
    const int tid = threadIdx.x;
    const int lane = tid & 63, wv = tid >> 6;   // wv in [0,16)
    const int w8 = wv >> 1, hh = wv & 1;
    const int lr = lane & 15, quad = lane >> 4;
    const int cA = 32 * w8 + 16 * hh + lr;      // this wave's gate column

    if (tid < 128) posD[tid] = 0.f;
    if (tid < 512) {
        owl[tid] = out_w[m * 512 + tid];
        cbA[tid] = b_ih0[m * 768 + tid] + b_hh0[m * 768 + tid];
        cb1A[tid] = b_ih1[m * 768 + tid] + b_hh1[m * 768 + tid];
    }
    if (tid < 256) {
        cbXn[tid] = f2bf(b_ih0[m * 768 + 512 + tid]);
        cbh0n[tid] = f2bf(b_hh0[m * 768 + 512 + tid]);
        cb1X[tid] = f2bf(b_ih1[m * 768 + 512 + tid]);
        cb1H[tid] = f2bf(b_hh1[m * 768 + 512 + tid]);
    }
    if (tid < 768) {
        cwp0h[tid] = f2bf(w_ih0_f[((size_t)m * 768 + tid) * 258 + 0]);
        cwp1h[tid] = f2bf(w_ih0_f[((size_t)m * 768 + tid) * 258 + 1]);
    }
#pragma unroll
    for (int i = 0; i < 16; ++i) {
        int idx = tid + i * 1024;
        int r = idx >> 8, k = idx & 255;
        short v = f2bf(context[(size_t)(b0 + r) * 256 + k]);
        ctxS[r * 264 + k] = v;
        h0a[r * 264 + k] = v;
        h1s[r * 264 + k] = v;
    }
    const float ob0v = out_b[m * 2 + 0], ob1v = out_b[m * 2 + 1];

    // Single per-wave stream base (96 tiles, consumption order).
    const short* pW = ws + (size_t)(m * 16 + w8 * 2 + hh) * 96 * 512 + lane * 8;
    // (L0 at +0, L1 at +48*512)

    __syncthreads();

    float cum0 = 0.f, cum1 = 0.f;

    for (int st = 0; st < T; ++st) {
        const short* h0c = (st & 1) ? h0b : h0a;   // current h0
        short* h0n_ = (st & 1) ? h0a : h0b;        // next h0 (no WAR hazard)

        // ======== layer 0 (merged rz+n; wave = one 16-col slice) ========
        {
            f32x4 arz[2][4], axn[4], ahn[4];
            {
                // per-lane scalars re-read from LDS (not held across steps)
                const int cz = 256 + cA, cn = 512 + cA;
                const float bAr = cbA[cA], bAz = cbA[cz];
                const float w0r = bf2f(cwp0h[cA]), w1r = bf2f(cwp1h[cA]);
                const float w0z = bf2f(cwp0h[cz]), w1z = bf2f(cwp1h[cz]);
                const float w0n = bf2f(cwp0h[cn]), w1n = bf2f(cwp1h[cn]);
                const float bXn = bf2f(cbXn[cA]), bHn = bf2f(cbh0n[cA]);
#pragma unroll
                for (int rt = 0; rt < 4; ++rt)
#pragma unroll
                    for (int r = 0; r < 4; ++r) {
                        int row = rt * 16 + quad * 4 + r;
                        float px = posD[row * 2], py = posD[row * 2 + 1];
                        arz[0][rt][r] = bAr + px * w0r + py * w1r;
                        arz[1][rt][r] = bAz + px * w0z + py * w1z;
                        axn[rt][r] = bXn + px * w0n + py * w1n;
                        ahn[rt][r] = bHn;
                    }
            }
            const short* q = pW;
#pragma unroll 1
            for (int ks = 0; ks < 8; ++ks) {
                bf16x8 a[4];
                {
                    bf16x8 b0 = *reinterpret_cast<const bf16x8*>(q);
                    bf16x8 b1 = *reinterpret_cast<const bf16x8*>(q + 512);
                    bf16x8 b2 = *reinterpret_cast<const bf16x8*>(q + 1024);
#pragma unroll
                    for (int rt = 0; rt < 4; ++rt)
                        a[rt] = *reinterpret_cast<const bf16x8*>(
                            ctxS + (rt * 16 + lr) * 264 + ks * 32 + quad * 8);
#pragma unroll
                    for (int rt = 0; rt < 4; ++rt)
                        arz[0][rt] = __builtin_amdgcn_mfma_f32_16x16x32_bf16(
                            a[rt], b0, arz[0][rt], 0, 0, 0);
#pragma unroll
                    for (int rt = 0; rt < 4; ++rt)
                        arz[1][rt] = __builtin_amdgcn_mfma_f32_16x16x32_bf16(
                            a[rt], b1, arz[1][rt], 0, 0, 0);
#pragma unroll
                    for (int rt = 0; rt < 4; ++rt)
                        axn[rt] = __builtin_amdgcn_mfma_f32_16x16x32_bf16(
                            a[rt], b2, axn[rt], 0, 0, 0);
                }
                {
                    bf16x8 c0 = *reinterpret_cast<const bf16x8*>(q + 1536);
                    bf16x8 c1 = *reinterpret_cast<const bf16x8*>(q + 2048);
                    bf16x8 c2 = *reinterpret_cast<const bf16x8*>(q + 2560);
#pragma unroll
                    for (int rt = 0; rt < 4; ++rt)
                        a[rt] = *reinterpret_cast<const bf16x8*>(
                            h0c + (rt * 16 + lr) * 264 + ks * 32 + quad * 8);
#pragma unroll
                    for (int rt = 0; rt < 4; ++rt)
                        arz[0][rt] = __builtin_amdgcn_mfma_f32_16x16x32_bf16(
                            a[rt], c0, arz[0][rt], 0, 0, 0);
#pragma unroll
                    for (int rt = 0; rt < 4; ++rt)
                        arz[1][rt] = __builtin_amdgcn_mfma_f32_16x16x32_bf16(
                            a[rt], c1, arz[1][rt], 0, 0, 0);
#pragma unroll
                    for (int rt = 0; rt < 4; ++rt)
                        ahn[rt] = __builtin_amdgcn_mfma_f32_16x16x32_bf16(
                            a[rt], c2, ahn[rt], 0, 0, 0);
                }
                q += 3072;
            }
            // no barrier: epilogue writes h0n_ (other buffer), no WAR hazard
#pragma unroll
            for (int rt = 0; rt < 4; ++rt)
#pragma unroll
                for (int r = 0; r < 4; ++r) {
                    int row = rt * 16 + quad * 4 + r;
                    float rr = fast_sigmoid(arz[0][rt][r]);
                    float zz = fast_sigmoid(arz[1][rt][r]);
                    float nn = fast_tanh(axn[rt][r] + rr * ahn[rt][r]);
                    float hold = bf2f(h0c[row * 264 + cA]);
                    h0n_[row * 264 + cA] = f2bf((1.f - zz) * nn + zz * hold);
                }
        }
        __syncthreads();  // B1: h0' visible

        // ======== layer 1 (merged rz+n) ========
        {
            f32x4 arz[2][4], axn[4], ahn[4];
            {
                const int cz = 256 + cA;
                const float bAr = cb1A[cA], bAz = cb1A[cz];
                const float bXv = bf2f(cb1X[cA]), bHv = bf2f(cb1H[cA]);
#pragma unroll
                for (int rt = 0; rt < 4; ++rt)
#pragma unroll
                    for (int r = 0; r < 4; ++r) {
                        arz[0][rt][r] = bAr;
                        arz[1][rt][r] = bAz;
                        axn[rt][r] = bXv;
                        ahn[rt][r] = bHv;
                    }
            }
            const short* q = pW + 48 * 512;
#pragma unroll 1
            for (int ks = 0; ks < 8; ++ks) {
                bf16x8 a[4];
                {
                    bf16x8 b0 = *reinterpret_cast<const bf16x8*>(q);
                    bf16x8 b1 = *reinterpret_cast<const bf16x8*>(q + 512);
                    bf16x8 b2 = *reinterpret_cast<const bf16x8*>(q + 1024);
#pragma unroll
                    for (int rt = 0; rt < 4; ++rt)
                        a[rt] = *reinterpret_cast<const bf16x8*>(
                            h0n_ + (rt * 16 + lr) * 264 + ks * 32 + quad * 8);
#pragma unroll
                    for (int rt = 0; rt < 4; ++rt)
                        arz[0][rt] = __builtin_amdgcn_mfma_f32_16x16x32_bf16(
                            a[rt], b0, arz[0][rt], 0, 0, 0);
#pragma unroll
                    for (int rt = 0; rt < 4; ++rt)
                        arz[1][rt] = __builtin_amdgcn_mfma_f32_16x16x32_bf16(
                            a[rt], b1, arz[1][rt], 0, 0, 0);
#pragma unroll
                    for (int rt = 0; rt < 4; ++rt)
                        axn[rt] = __builtin_amdgcn_mfma_f32_16x16x32_bf16(
                            a[rt], b2, axn[rt], 0, 0, 0);
                }
                {
                    bf16x8 c0 = *reinterpret_cast<const bf16x8*>(q + 1536);
                    bf16x8 c1 = *reinterpret_cast<const bf16x8*>(q + 2048);
                    bf16x8 c2 = *reinterpret_cast<const bf16x8*>(q + 2560);
#pragma unroll
                    for (int rt = 0; rt < 4; ++rt)
                        a[rt] = *reinterpret_cast<const bf16x8*>(
                            h1s + (rt * 16 + lr) * 264 + ks * 32 + quad * 8);
#pragma unroll
                    for (int rt = 0; rt < 4; ++rt)
                        arz[0][rt] = __builtin_amdgcn_mfma_f32_16x16x32_bf16(
                            a[rt], c0, arz[0][rt], 0, 0, 0);
#pragma unroll
                    for (int rt = 0; rt < 4; ++rt)
                        arz[1][rt] = __builtin_amdgcn_mfma_f32_16x16x32_bf16(
                            a[rt], c1, arz[1][rt], 0, 0, 0);
#pragma unroll
                    for (int rt = 0; rt < 4; ++rt)
                        ahn[rt] = __builtin_amdgcn_mfma_f32_16x16x32_bf16(
                            a[rt], c2, ahn[rt], 0, 0, 0);
                }
                q += 3072;
            }
            __syncthreads();  // B2: all h1 reads complete
#pragma unroll
            for (int rt = 0; rt < 4; ++rt)
#pragma unroll
                for (int r = 0; r < 4; ++r) {
                    int row = rt * 16 + quad * 4 + r;
                    float rr = fast_sigmoid(arz[0][rt][r]);
                    float zz = fast_sigmoid(arz[1][rt][r]);
                    float nn = fast_tanh(axn[rt][r] + rr * ahn[rt][r]);
                    float hold = bf2f(h1s[row * 264 + cA]);
                    h1s[row * 264 + cA] = f2bf((1.f - zz) * nn + zz * hold);
                }
        }
        __syncthreads();  // B3: h1' visible

        // ---------------- delta = h1' @ ow.T + ob ; cumsum -> out
        {
            int brow = tid >> 4, p = tid & 15;   // 64 rows x 16 partials
            float d0 = 0.f, d1 = 0.f;
#pragma unroll
            for (int j = 0; j < 2; ++j) {
                int cb = ((p + brow) & 15) * 16 + j * 8;
                bf16x8 hv8 = *reinterpret_cast<const bf16x8*>(h1s + brow * 264 + cb);
#pragma unroll
                for (int i = 0; i < 8; ++i) {
                    float hv = bf2f(hv8[i]);
                    d0 += hv * owl[cb + i];
                    d1 += hv * owl[256 + cb + i];
                }
            }
            d0 += __shfl_xor(d0, 1); d0 += __shfl_xor(d0, 2);
            d0 += __shfl_xor(d0, 4); d0 += __shfl_xor(d0, 8);
            d1 += __shfl_xor(d1, 1); d1 += __shfl_xor(d1, 2);
            d1 += __shfl_xor(d1, 4); d1 += __shfl_xor(d1, 8);
            d0 += ob0v;
            d1 += ob1v;
            if (p == 0) {
                cum0 += d0;
                cum1 += d1;
                size_t o = (((size_t)(b0 + brow) * 3 + m) * (size_t)T + st) * 2;
                out[o] = cum0;
                out[o + 1] = cum1;
                posD[brow * 2] = d0;
                posD[brow * 2 + 1] = d1;
            }
        }
        __syncthreads();  // B4: posD ready
    }
}

extern "C" void kernel_launch(void* const* d_in, const int* in_sizes, int n_in,
                              void* d_out, int out_size, void* d_ws, size_t ws_size,
                              hipStream_t stream) {
    const float* context = (const float*)d_in[0];
    const float* mp_w1 = (const float*)d_in[1];
    const float* mp_b1 = (const float*)d_in[2];
    const float* mp_w2 = (const float*)d_in[3];
    const float* mp_b2 = (const float*)d_in[4];
    const float* w_ih0 = (const float*)d_in[5];
    const float* w_hh0 = (const float*)d_in[6];
    const float* b_ih0 = (const float*)d_in[7];
    const float* b_hh0 = (const float*)d_in[8];
    const float* w_ih1 = (const float*)d_in[9];
    const float* w_hh1 = (const float*)d_in[10];
    const float* b_ih1 = (const float*)d_in[11];
    const float* b_hh1 = (const float*)d_in[12];
    const float* out_w = (const float*)d_in[13];
    const float* out_b = (const float*)d_in[14];
    const int* pT = (const int*)d_in[15];
    float* out = (float*)d_out;
    short* ws = (short*)d_ws;

    const int B = in_sizes[0] / 256;                      // 4096
    const int ntiles = B / 64;                            // 64
    const long probs_off = (long)out_size - (long)B * 3;

    prep_kernel<<<4608, 64, 0, stream>>>(w_ih0, w_hh0, w_ih1, w_hh1, ws);
    modeprobs_kernel<<<B / 64, 256, 0, stream>>>(context, mp_w1, mp_b1, mp_w2,
                                                 mp_b2, out, probs_off);
    const int nslots = (ntiles + 1) / 2;
    decoder_kernel<<<8 * nslots, 1024, 0, stream>>>(
        context, w_ih0, b_ih0, b_hh0, b_ih1, b_hh1, out_w, out_b, ws, out, pT,
        ntiles);
}